// Round 11
// baseline (403.990 us; speedup 1.0000x reference)
//
#include <hip/hip_runtime.h>

#define DEV __device__ __forceinline__

typedef __attribute__((ext_vector_type(8))) short bf16x8;
typedef __attribute__((ext_vector_type(4))) float f32x4;

static constexpr int Bn = 8;
static constexpr int Sn = 2048;
static constexpr int Dn = 1024;
static constexpr int Mtot = Bn * Sn;   // 16384

// core B (qk/v): ring-3, tile 256x128, BK=32 -> 24KB/buf, 72KB, 2 blk/CU
static constexpr int ABUF = 8192;      // shorts: A 256x32
static constexpr int TBUF = 12288;     // shorts per ring buffer
// core A (scores/pv): ring-4, tile 256x256, BK=32 -> 32KB/buf, 128KB, 1 blk/CU
static constexpr int BUFS_A = 16384;   // shorts per ring buffer
static constexpr int BHALF_A = 8192;   // shorts: A half (256x32)

DEV void gload_lds16(const void* g, void* l) {
  __builtin_amdgcn_global_load_lds(
      (const __attribute__((address_space(1))) void*)g,
      (__attribute__((address_space(3))) void*)l, 16, 0, 0);
}

DEV float bf2f(unsigned short u) {
  union { unsigned int i; float f; } c;
  c.i = ((unsigned int)u) << 16;
  return c.f;
}
DEV unsigned short f2bf(float f) {
  union { float f; unsigned int i; } c;
  c.f = f;
  unsigned int lsb = (c.i >> 16) & 1u;
  return (unsigned short)((c.i + 0x7fffu + lsb) >> 16);
}

// ---------------------------------------------------------------- prep
__global__ __launch_bounds__(256) void prep_kernel(const float* __restrict__ x,
                                                   unsigned short* __restrict__ xbf,
                                                   float* __restrict__ masks) {
  const int w = threadIdx.x >> 6, l = threadIdx.x & 63;
  const int row = blockIdx.x * 4 + w;
  const float* xr = x + (size_t)row * Dn;
  unsigned short* xo = xbf + (size_t)row * Dn;
  float s = 0.f;
  #pragma unroll
  for (int i = 0; i < 4; i++) {
    float4 v = ((const float4*)xr)[i * 64 + l];
    s += (v.x + v.y) + (v.z + v.w);
    unsigned int p0 = (unsigned int)f2bf(v.x) | ((unsigned int)f2bf(v.y) << 16);
    unsigned int p1 = (unsigned int)f2bf(v.z) | ((unsigned int)f2bf(v.w) << 16);
    *(uint2*)&xo[i * 256 + l * 4] = make_uint2(p0, p1);
  }
  #pragma unroll
  for (int off = 32; off > 0; off >>= 1) s += __shfl_xor(s, off);
  if (l == 0) masks[row] = sinf(fabsf(s));
}

// ---------------------------------------------------------------- Wt
__global__ __launch_bounds__(256) void wt_kernel(const float* __restrict__ Wq,
                                                 const float* __restrict__ Wk,
                                                 const float* __restrict__ Wv,
                                                 unsigned short* __restrict__ Wt) {
  const float* W = blockIdx.z == 0 ? Wq : (blockIdx.z == 1 ? Wk : Wv);
  unsigned short* out = Wt + (size_t)blockIdx.z * Dn * Dn;
  __shared__ float tile[32][33];
  const int r0 = blockIdx.y * 32, c0 = blockIdx.x * 32;
  const int t = threadIdx.x;
  {
    const int r = t >> 3, c4 = (t & 7) * 4;
    float4 v = *(const float4*)&W[(size_t)(r0 + r) * Dn + c0 + c4];
    tile[r][c4 + 0] = v.x; tile[r][c4 + 1] = v.y;
    tile[r][c4 + 2] = v.z; tile[r][c4 + 3] = v.w;
  }
  __syncthreads();
  {
    const int f = t >> 3, d4 = (t & 7) * 4;
    unsigned short o[4];
    #pragma unroll
    for (int i = 0; i < 4; i++) o[i] = f2bf(tile[d4 + i][f]);
    unsigned int p0 = (unsigned int)o[0] | ((unsigned int)o[1] << 16);
    unsigned int p1 = (unsigned int)o[2] | ((unsigned int)o[3] << 16);
    *(uint2*)&out[(size_t)(c0 + f) * Dn + r0 + d4] = make_uint2(p0, p1);
  }
}

// ---------------------------------------------------------------- core B dual:
// two 256x128 tiles sharing A; global steps g=0..63 (NT=32/tile), ring-3,
// distance-2 staging runs CONTINUOUSLY across the tile boundary (vmcnt never
// drains mid-kernel). epi(tt) is called with acc at each tile's end; its
// global stores only make the counted waits conservative.
template <typename EPI>
DEV void gemmB_dual(const unsigned short* __restrict__ Ag, int lda,
                    const unsigned short* __restrict__ Bg0,
                    const unsigned short* __restrict__ Bg1, int ldb,
                    unsigned short* lds, f32x4 (&acc)[4][4], EPI epi) {
  const int tid = threadIdx.x;
  const int l = tid & 63, w = tid >> 6;
  const int wr = w >> 1, wc = w & 1;
  const int lr = l & 15, lk = l >> 4;

  #pragma unroll
  for (int mi = 0; mi < 4; mi++)
    #pragma unroll
    for (int ni = 0; ni < 4; ni++)
      #pragma unroll
      for (int q = 0; q < 4; q++) acc[mi][ni][q] = 0.f;

  int offA[4], offB[4];
  #pragma unroll
  for (int mi = 0; mi < 4; mi++) {
    const int row = wr * 64 + mi * 16 + lr;
    offA[mi] = (row * 4 + (lk ^ ((row >> 1) & 3))) * 8;
  }
  #pragma unroll
  for (int ni = 0; ni < 4; ni++) {
    const int row = wc * 64 + ni * 16 + lr;
    offB[ni] = (row * 4 + (lk ^ ((row >> 1) & 3))) * 8;
  }
  int sA[2], dA[2], sB, dB;
  #pragma unroll
  for (int i = 0; i < 2; i++) {
    const int ci = i * 512 + tid;
    const int row = ci >> 2, c = (ci & 3) ^ ((row >> 1) & 3);
    sA[i] = row * lda + c * 8;
    dA[i] = ci * 8;
  }
  {
    const int ci = tid;
    const int row = ci >> 2, c = (ci & 3) ^ ((row >> 1) & 3);
    sB = row * ldb + c * 8;
    dB = ci * 8;
  }

  const int NT = 32, G = 64;
  auto bsrc = [&](int g) {
    return (g >= NT) ? Bg1 + (size_t)(g - NT) * 32 : Bg0 + (size_t)g * 32;
  };
  auto akt = [&](int g) { return (g >= NT ? g - NT : g) * 32; };

  #pragma unroll
  for (int t = 0; t < 2; t++) {
    unsigned short* bf = lds + t * TBUF;
    gload_lds16(Ag + sA[0] + akt(t), bf + dA[0]);
    gload_lds16(Ag + sA[1] + akt(t), bf + dA[1]);
    gload_lds16(bsrc(t) + sB, bf + ABUF + dB);
  }
  asm volatile("s_waitcnt vmcnt(3)\n\ts_barrier" ::: "memory");

  for (int g = 0; g < G; g++) {
    unsigned short* bc = lds + (g % 3) * TBUF;
    unsigned short* b2 = lds + ((g + 2) % 3) * TBUF;
    const bool st = (g + 2 < G);

    bf16x8 af[4], bv[4];
    #pragma unroll
    for (int mi = 0; mi < 4; mi++) af[mi] = *(const bf16x8*)(bc + offA[mi]);
    #pragma unroll
    for (int ni = 0; ni < 4; ni++) bv[ni] = *(const bf16x8*)(bc + ABUF + offB[ni]);

    if (st) {
      const int kt = akt(g + 2);
      gload_lds16(Ag + sA[0] + kt, b2 + dA[0]);
      gload_lds16(Ag + sA[1] + kt, b2 + dA[1]);
    }
    __builtin_amdgcn_s_setprio(1);
    #pragma unroll
    for (int mi = 0; mi < 4; mi++) {
      acc[mi][0] = __builtin_amdgcn_mfma_f32_16x16x32_bf16(af[mi], bv[0], acc[mi][0], 0, 0, 0);
      acc[mi][1] = __builtin_amdgcn_mfma_f32_16x16x32_bf16(af[mi], bv[1], acc[mi][1], 0, 0, 0);
    }
    __builtin_amdgcn_s_setprio(0);
    if (st) {
      gload_lds16(bsrc(g + 2) + sB, b2 + ABUF + dB);
    }
    __builtin_amdgcn_s_setprio(1);
    #pragma unroll
    for (int mi = 0; mi < 4; mi++) {
      acc[mi][2] = __builtin_amdgcn_mfma_f32_16x16x32_bf16(af[mi], bv[2], acc[mi][2], 0, 0, 0);
      acc[mi][3] = __builtin_amdgcn_mfma_f32_16x16x32_bf16(af[mi], bv[3], acc[mi][3], 0, 0, 0);
    }
    __builtin_amdgcn_s_setprio(0);

    if (g + 2 < G) {
      asm volatile("s_waitcnt vmcnt(3)\n\ts_barrier" ::: "memory");
    } else if (g + 1 < G) {
      asm volatile("s_waitcnt vmcnt(0)\n\ts_barrier" ::: "memory");
    }
    if (g == NT - 1) {
      epi(0);
      #pragma unroll
      for (int mi = 0; mi < 4; mi++)
        #pragma unroll
        for (int ni = 0; ni < 4; ni++)
          #pragma unroll
          for (int q = 0; q < 4; q++) acc[mi][ni][q] = 0.f;
    }
  }
  epi(1);
}

// ---------------------------------------------------------------- core B single (for V)
DEV void gemmB(const unsigned short* __restrict__ Ag, int lda,
               const unsigned short* __restrict__ Bg, int ldb,
               int K, unsigned short* lds, f32x4 acc[4][4]) {
  const int tid = threadIdx.x;
  const int l = tid & 63, w = tid >> 6;
  const int wr = w >> 1, wc = w & 1;
  const int lr = l & 15, lk = l >> 4;

  #pragma unroll
  for (int mi = 0; mi < 4; mi++)
    #pragma unroll
    for (int ni = 0; ni < 4; ni++)
      #pragma unroll
      for (int q = 0; q < 4; q++) acc[mi][ni][q] = 0.f;

  int offA[4], offB[4];
  #pragma unroll
  for (int mi = 0; mi < 4; mi++) {
    const int row = wr * 64 + mi * 16 + lr;
    offA[mi] = (row * 4 + (lk ^ ((row >> 1) & 3))) * 8;
  }
  #pragma unroll
  for (int ni = 0; ni < 4; ni++) {
    const int row = wc * 64 + ni * 16 + lr;
    offB[ni] = (row * 4 + (lk ^ ((row >> 1) & 3))) * 8;
  }
  int sA[2], dA[2], sB, dB;
  #pragma unroll
  for (int i = 0; i < 2; i++) {
    const int ci = i * 512 + tid;
    const int row = ci >> 2, c = (ci & 3) ^ ((row >> 1) & 3);
    sA[i] = row * lda + c * 8;
    dA[i] = ci * 8;
  }
  {
    const int ci = tid;
    const int row = ci >> 2, c = (ci & 3) ^ ((row >> 1) & 3);
    sB = row * ldb + c * 8;
    dB = ci * 8;
  }

  const int NT = K >> 5;
  unsigned short* bc = lds;
  unsigned short* b1 = lds + TBUF;
  unsigned short* b2 = lds + 2 * TBUF;

  #pragma unroll
  for (int t = 0; t < 2; t++) {
    unsigned short* bf = lds + t * TBUF;
    gload_lds16(Ag + sA[0] + t * 32, bf + dA[0]);
    gload_lds16(Ag + sA[1] + t * 32, bf + dA[1]);
    gload_lds16(Bg + sB + t * 32, bf + ABUF + dB);
  }
  asm volatile("s_waitcnt vmcnt(3)\n\ts_barrier" ::: "memory");

  for (int t = 0; t < NT; t++) {
    const bool st = (t + 2 < NT);
    const int kt = (t + 2) * 32;

    bf16x8 af[4], bv[4];
    #pragma unroll
    for (int mi = 0; mi < 4; mi++) af[mi] = *(const bf16x8*)(bc + offA[mi]);
    #pragma unroll
    for (int ni = 0; ni < 4; ni++) bv[ni] = *(const bf16x8*)(bc + ABUF + offB[ni]);

    if (st) {
      gload_lds16(Ag + sA[0] + kt, b2 + dA[0]);
      gload_lds16(Ag + sA[1] + kt, b2 + dA[1]);
    }
    __builtin_amdgcn_s_setprio(1);
    #pragma unroll
    for (int mi = 0; mi < 4; mi++) {
      acc[mi][0] = __builtin_amdgcn_mfma_f32_16x16x32_bf16(af[mi], bv[0], acc[mi][0], 0, 0, 0);
      acc[mi][1] = __builtin_amdgcn_mfma_f32_16x16x32_bf16(af[mi], bv[1], acc[mi][1], 0, 0, 0);
    }
    __builtin_amdgcn_s_setprio(0);
    if (st) {
      gload_lds16(Bg + sB + kt, b2 + ABUF + dB);
    }
    __builtin_amdgcn_s_setprio(1);
    #pragma unroll
    for (int mi = 0; mi < 4; mi++) {
      acc[mi][2] = __builtin_amdgcn_mfma_f32_16x16x32_bf16(af[mi], bv[2], acc[mi][2], 0, 0, 0);
      acc[mi][3] = __builtin_amdgcn_mfma_f32_16x16x32_bf16(af[mi], bv[3], acc[mi][3], 0, 0, 0);
    }
    __builtin_amdgcn_s_setprio(0);

    if (t + 2 < NT) {
      asm volatile("s_waitcnt vmcnt(3)\n\ts_barrier" ::: "memory");
    } else if (t + 1 < NT) {
      asm volatile("s_waitcnt vmcnt(0)\n\ts_barrier" ::: "memory");
    }
    unsigned short* tmp = bc; bc = b1; b1 = b2; b2 = tmp;
  }
}

// ---------------------------------------------------------------- core A dual:
// two 256x256 tiles sharing A; g=0..63, ring-4, distance-3, vmcnt(8).
template <typename EPI>
DEV void gemmA_dual(const unsigned short* __restrict__ Ag, int lda,
                    const unsigned short* __restrict__ Bg0,
                    const unsigned short* __restrict__ Bg1, int ldb,
                    unsigned short* lds, f32x4 (&acc)[8][4], EPI epi) {
  const int tid = threadIdx.x;
  const int l = tid & 63, w = tid >> 6;
  const int wr = w >> 2, wc = w & 3;
  const int lr = l & 15, lk = l >> 4;

  #pragma unroll
  for (int mi = 0; mi < 8; mi++)
    #pragma unroll
    for (int ni = 0; ni < 4; ni++)
      #pragma unroll
      for (int q = 0; q < 4; q++) acc[mi][ni][q] = 0.f;

  int offA[8], offB[4];
  #pragma unroll
  for (int mi = 0; mi < 8; mi++) {
    const int row = wr * 128 + mi * 16 + lr;
    const int L = row >> 1, p = ((row & 1) * 4 + lk) ^ (L & 7);
    offA[mi] = L * 64 + p * 8;
  }
  #pragma unroll
  for (int ni = 0; ni < 4; ni++) {
    const int row = wc * 64 + ni * 16 + lr;
    const int L = row >> 1, p = ((row & 1) * 4 + lk) ^ (L & 7);
    offB[ni] = L * 64 + p * 8;
  }
  int sA[2], sB[2], dO[2];
  #pragma unroll
  for (int i = 0; i < 2; i++) {
    const int ci = i * 512 + tid;
    const int L = ci >> 3, p = ci & 7, e = p ^ (L & 7);
    const int grow = 2 * L + (e >> 2), gkc = e & 3;
    sA[i] = grow * lda + gkc * 8;
    sB[i] = grow * ldb + gkc * 8;
    dO[i] = ci * 8;
  }

  const int NT = 32, G = 64;
  auto bsrc = [&](int g) {
    return (g >= NT) ? Bg1 + (size_t)(g - NT) * 32 : Bg0 + (size_t)g * 32;
  };
  auto akt = [&](int g) { return (g >= NT ? g - NT : g) * 32; };

  #pragma unroll
  for (int t = 0; t < 3; t++) {
    unsigned short* bf = lds + t * BUFS_A;
    gload_lds16(Ag + sA[0] + akt(t), bf + dO[0]);
    gload_lds16(Ag + sA[1] + akt(t), bf + dO[1]);
    gload_lds16(bsrc(t) + sB[0], bf + BHALF_A + dO[0]);
    gload_lds16(bsrc(t) + sB[1], bf + BHALF_A + dO[1]);
  }
  asm volatile("s_waitcnt vmcnt(8)\n\ts_barrier" ::: "memory");

  for (int g = 0; g < G; g++) {
    unsigned short* bufc = lds + (g & 3) * BUFS_A;
    unsigned short* bufs = lds + ((g + 3) & 3) * BUFS_A;
    const bool st = (g + 3 < G);
    const int kt = akt(g + 3);

    bf16x8 af[8], bv[4];
    #pragma unroll
    for (int mi = 0; mi < 8; mi++) af[mi] = *(const bf16x8*)(bufc + offA[mi]);
    bv[0] = *(const bf16x8*)(bufc + BHALF_A + offB[0]);
    bv[1] = *(const bf16x8*)(bufc + BHALF_A + offB[1]);
    if (st) {
      gload_lds16(Ag + sA[0] + kt, bufs + dO[0]);
      gload_lds16(Ag + sA[1] + kt, bufs + dO[1]);
    }
    __builtin_amdgcn_s_setprio(1);
    #pragma unroll
    for (int mi = 0; mi < 8; mi++) {
      acc[mi][0] = __builtin_amdgcn_mfma_f32_16x16x32_bf16(af[mi], bv[0], acc[mi][0], 0, 0, 0);
      acc[mi][1] = __builtin_amdgcn_mfma_f32_16x16x32_bf16(af[mi], bv[1], acc[mi][1], 0, 0, 0);
    }
    __builtin_amdgcn_s_setprio(0);
    bv[2] = *(const bf16x8*)(bufc + BHALF_A + offB[2]);
    bv[3] = *(const bf16x8*)(bufc + BHALF_A + offB[3]);
    if (st) {
      gload_lds16(bsrc(g + 3) + sB[0], bufs + BHALF_A + dO[0]);
      gload_lds16(bsrc(g + 3) + sB[1], bufs + BHALF_A + dO[1]);
    }
    __builtin_amdgcn_s_setprio(1);
    #pragma unroll
    for (int mi = 0; mi < 8; mi++) {
      acc[mi][2] = __builtin_amdgcn_mfma_f32_16x16x32_bf16(af[mi], bv[2], acc[mi][2], 0, 0, 0);
      acc[mi][3] = __builtin_amdgcn_mfma_f32_16x16x32_bf16(af[mi], bv[3], acc[mi][3], 0, 0, 0);
    }
    __builtin_amdgcn_s_setprio(0);

    if (g < G - 3) {
      asm volatile("s_waitcnt vmcnt(8)\n\ts_barrier" ::: "memory");
    } else if (g == G - 3) {
      asm volatile("s_waitcnt vmcnt(4)\n\ts_barrier" ::: "memory");
    } else if (g == G - 2) {
      asm volatile("s_waitcnt vmcnt(0)\n\ts_barrier" ::: "memory");
    }
    if (g == NT - 1) {
      epi(0);
      #pragma unroll
      for (int mi = 0; mi < 8; mi++)
        #pragma unroll
        for (int ni = 0; ni < 4; ni++)
          #pragma unroll
          for (int q = 0; q < 4; q++) acc[mi][ni][q] = 0.f;
    }
  }
  epi(1);
}

// ---------------------------------------------------------------- core A single (pv)
DEV void gemmA(const unsigned short* __restrict__ Ag, int lda,
               const unsigned short* __restrict__ Bg, int ldb,
               int K, unsigned short* lds, f32x4 acc[8][4]) {
  const int tid = threadIdx.x;
  const int l = tid & 63, w = tid >> 6;
  const int wr = w >> 2, wc = w & 3;
  const int lr = l & 15, lk = l >> 4;

  #pragma unroll
  for (int mi = 0; mi < 8; mi++)
    #pragma unroll
    for (int ni = 0; ni < 4; ni++)
      #pragma unroll
      for (int q = 0; q < 4; q++) acc[mi][ni][q] = 0.f;

  int offA[8], offB[4];
  #pragma unroll
  for (int mi = 0; mi < 8; mi++) {
    const int row = wr * 128 + mi * 16 + lr;
    const int L = row >> 1, p = ((row & 1) * 4 + lk) ^ (L & 7);
    offA[mi] = L * 64 + p * 8;
  }
  #pragma unroll
  for (int ni = 0; ni < 4; ni++) {
    const int row = wc * 64 + ni * 16 + lr;
    const int L = row >> 1, p = ((row & 1) * 4 + lk) ^ (L & 7);
    offB[ni] = L * 64 + p * 8;
  }
  int sA[2], sB[2], dO[2];
  #pragma unroll
  for (int i = 0; i < 2; i++) {
    const int ci = i * 512 + tid;
    const int L = ci >> 3, p = ci & 7, e = p ^ (L & 7);
    const int grow = 2 * L + (e >> 2), gkc = e & 3;
    sA[i] = grow * lda + gkc * 8;
    sB[i] = grow * ldb + gkc * 8;
    dO[i] = ci * 8;
  }

  const int NT = K >> 5;
  #pragma unroll
  for (int t = 0; t < 3; t++) {
    unsigned short* bf = lds + t * BUFS_A;
    gload_lds16(Ag + sA[0] + t * 32, bf + dO[0]);
    gload_lds16(Ag + sA[1] + t * 32, bf + dO[1]);
    gload_lds16(Bg + sB[0] + t * 32, bf + BHALF_A + dO[0]);
    gload_lds16(Bg + sB[1] + t * 32, bf + BHALF_A + dO[1]);
  }
  asm volatile("s_waitcnt vmcnt(8)\n\ts_barrier" ::: "memory");

  for (int t = 0; t < NT; t++) {
    unsigned short* bufc = lds + (t & 3) * BUFS_A;
    unsigned short* bufs = lds + ((t + 3) & 3) * BUFS_A;
    const bool st = (t + 3 < NT);
    const int kt = (t + 3) * 32;

    bf16x8 af[8], bv[4];
    #pragma unroll
    for (int mi = 0; mi < 8; mi++) af[mi] = *(const bf16x8*)(bufc + offA[mi]);
    bv[0] = *(const bf16x8*)(bufc + BHALF_A + offB[0]);
    bv[1] = *(const bf16x8*)(bufc + BHALF_A + offB[1]);
    if (st) {
      gload_lds16(Ag + sA[0] + kt, bufs + dO[0]);
      gload_lds16(Ag + sA[1] + kt, bufs + dO[1]);
    }
    __builtin_amdgcn_s_setprio(1);
    #pragma unroll
    for (int mi = 0; mi < 8; mi++) {
      acc[mi][0] = __builtin_amdgcn_mfma_f32_16x16x32_bf16(af[mi], bv[0], acc[mi][0], 0, 0, 0);
      acc[mi][1] = __builtin_amdgcn_mfma_f32_16x16x32_bf16(af[mi], bv[1], acc[mi][1], 0, 0, 0);
    }
    __builtin_amdgcn_s_setprio(0);
    bv[2] = *(const bf16x8*)(bufc + BHALF_A + offB[2]);
    bv[3] = *(const bf16x8*)(bufc + BHALF_A + offB[3]);
    if (st) {
      gload_lds16(Bg + sB[0] + kt, bufs + BHALF_A + dO[0]);
      gload_lds16(Bg + sB[1] + kt, bufs + BHALF_A + dO[1]);
    }
    __builtin_amdgcn_s_setprio(1);
    #pragma unroll
    for (int mi = 0; mi < 8; mi++) {
      acc[mi][2] = __builtin_amdgcn_mfma_f32_16x16x32_bf16(af[mi], bv[2], acc[mi][2], 0, 0, 0);
      acc[mi][3] = __builtin_amdgcn_mfma_f32_16x16x32_bf16(af[mi], bv[3], acc[mi][3], 0, 0, 0);
    }
    __builtin_amdgcn_s_setprio(0);

    if (t < NT - 3) {
      asm volatile("s_waitcnt vmcnt(8)\n\ts_barrier" ::: "memory");
    } else if (t == NT - 3) {
      asm volatile("s_waitcnt vmcnt(4)\n\ts_barrier" ::: "memory");
    } else if (t == NT - 2) {
      asm volatile("s_waitcnt vmcnt(0)\n\ts_barrier" ::: "memory");
    }
  }
}

// ---------------------------------------------------------------- QK (core B dual)
// 512 blocks: which(2) x m(64) x npair(4); per block n0 and n0+128 share A.
__global__ __launch_bounds__(512, 4) void qk_kernel(
    const unsigned short* __restrict__ xbf, const unsigned short* __restrict__ Wt,
    const float* __restrict__ bq, const float* __restrict__ bk,
    unsigned short* __restrict__ qo, unsigned short* __restrict__ ko) {
  __shared__ __align__(16) unsigned short lds[3 * TBUF];
  const int orig = blockIdx.x;
  const int wg = (orig & 7) * 64 + (orig >> 3);    // bijective XCD swizzle
  const int which = wg >> 8;
  const int rem = wg & 255;
  const int m0 = (rem >> 2) * 256, n0 = (rem & 3) * 256;
  const unsigned short* Ag = xbf + (size_t)m0 * Dn;
  const unsigned short* Bg0 = Wt + (size_t)which * Dn * Dn + (size_t)n0 * Dn;
  const unsigned short* Bg1 = Bg0 + (size_t)128 * Dn;

  const float* bias = which == 0 ? bq : bk;
  unsigned short* out = which == 0 ? qo : ko;
  const int tid = threadIdx.x;
  const int l = tid & 63, w = tid >> 6;
  const int wr = w >> 1, wc = w & 1;
  const int lr = l & 15, lk = l >> 4;

  f32x4 acc[4][4];
  gemmB_dual(Ag, Dn, Bg0, Bg1, Dn, lds, acc, [&](int tt) {
    const int nb = n0 + tt * 128;
    #pragma unroll
    for (int mi = 0; mi < 4; mi++) {
      #pragma unroll
      for (int ni = 0; ni < 4; ni++) {
        const int col = nb + wc * 64 + ni * 16 + lr;
        const float bcol = bias[col];
        #pragma unroll
        for (int j = 0; j < 4; j++) {
          const int row = m0 + wr * 64 + mi * 16 + lk * 4 + j;
          out[(size_t)row * Dn + col] = f2bf(fmaxf(acc[mi][ni][j] + bcol, 0.f));
        }
      }
    }
  });
}

// ---------------------------------------------------------------- V (core B single)
__global__ __launch_bounds__(512, 4) void v_kernel(
    const unsigned short* __restrict__ xbf, const unsigned short* __restrict__ Wt,
    const float* __restrict__ bv_, unsigned short* __restrict__ vT) {
  __shared__ __align__(16) unsigned short lds[3 * TBUF];
  const int orig = blockIdx.x;                     // 512 blocks
  const int wg = (orig & 7) * 64 + (orig >> 3);
  const int m0 = (wg >> 3) * 256, n0 = (wg & 7) * 128;
  const unsigned short* Ag = xbf + (size_t)m0 * Dn;
  const unsigned short* Bg = Wt + (size_t)2 * Dn * Dn + (size_t)n0 * Dn;
  f32x4 acc[4][4];
  gemmB(Ag, Dn, Bg, Dn, Dn, lds, acc);

  const int tid = threadIdx.x;
  const int l = tid & 63, w = tid >> 6;
  const int wr = w >> 1, wc = w & 1;
  const int lr = l & 15, lk = l >> 4;

  // single-pass transpose: [128 d][256 s] swizzled LDS buffer (64KB)
  const int b = m0 >> 11;
  const int s0g = m0 & (Sn - 1);
  __syncthreads();  // staging LDS dead
  #pragma unroll
  for (int mi = 0; mi < 4; mi++) {
    const int sc = wr * 16 + mi * 4 + lk;   // 8B chunk of 4 s-values
    #pragma unroll
    for (int ni = 0; ni < 4; ni++) {
      const int d = wc * 64 + ni * 16 + lr;
      const float bcol = bv_[n0 + d];
      unsigned short o0 = f2bf(fmaxf(acc[mi][ni][0] + bcol, 0.f));
      unsigned short o1 = f2bf(fmaxf(acc[mi][ni][1] + bcol, 0.f));
      unsigned short o2 = f2bf(fmaxf(acc[mi][ni][2] + bcol, 0.f));
      unsigned short o3 = f2bf(fmaxf(acc[mi][ni][3] + bcol, 0.f));
      const int scp = sc ^ (d & 63);
      *(uint2*)&lds[d * 256 + scp * 4] =
          make_uint2((unsigned int)o0 | ((unsigned int)o1 << 16),
                     (unsigned int)o2 | ((unsigned int)o3 << 16));
    }
  }
  __syncthreads();
  #pragma unroll
  for (int it = 0; it < 16; it++) {
    const int lin = it * 512 + tid;
    const int d = lin >> 6, sc = lin & 63;
    const int scp = sc ^ (d & 63);
    uint2 v = *(const uint2*)&lds[d * 256 + scp * 4];
    *(uint2*)&vT[((size_t)b * Dn + n0 + d) * Sn + s0g + sc * 4] = v;
  }
}

// ---------------------------------------------------------------- scores (core A dual)
// 256 blocks: b(8) x m(8) x npair(4); per block n0 and n0+256 share A (=q rows).
// psum lives in a dedicated LDS region beyond the ring (no overlap with staging).
__global__ __launch_bounds__(512, 2) void scores_kernel(
    const unsigned short* __restrict__ qbf, const unsigned short* __restrict__ kbf,
    const float* __restrict__ masks, unsigned short* __restrict__ P,
    float* __restrict__ lpart) {
  __shared__ __align__(16) unsigned short lds[4 * BUFS_A + 2048];
  const int orig = blockIdx.x;
  const int wg = (orig & 7) * 32 + (orig >> 3);
  const int b = wg >> 5;
  const int rem = wg & 31;
  const int m0 = (rem >> 2) * 256, n0 = (rem & 3) * 512;
  const unsigned short* Ag = qbf + ((size_t)b * Sn + m0) * Dn;
  const unsigned short* Bg0 = kbf + ((size_t)b * Sn + n0) * Dn;
  const unsigned short* Bg1 = Bg0 + (size_t)256 * Dn;

  const int tid = threadIdx.x;
  const int l = tid & 63, w = tid >> 6;
  const int wr = w >> 2, wc = w & 3;
  const int lr = l & 15, lk = l >> 4;
  float* psum = (float*)(lds + 4 * BUFS_A);   // 256x4 floats, own region
  unsigned short* Pb = P + (size_t)b * Sn * Sn;

  f32x4 acc[8][4];
  gemmA_dual(Ag, Dn, Bg0, Bg1, Dn, lds, acc, [&](int tt) {
    const int nb = n0 + tt * 256;
    float mkv[4];
    #pragma unroll
    for (int ni = 0; ni < 4; ni++)
      mkv[ni] = masks[b * Sn + nb + wc * 64 + ni * 16 + lr];
    __syncthreads();   // protect psum reuse across tiles
    #pragma unroll
    for (int mi = 0; mi < 8; mi++) {
      #pragma unroll
      for (int j = 0; j < 4; j++) {
        const int rloc = wr * 128 + mi * 16 + lk * 4 + j;
        const size_t rbase = (size_t)(m0 + rloc) * Sn;
        float rsum = 0.f;
        #pragma unroll
        for (int ni = 0; ni < 4; ni++) {
          const int col = nb + wc * 64 + ni * 16 + lr;
          const float p = (mkv[ni] == 0.f) ? 0.f : __expf(acc[mi][ni][j] * 0.03125f);
          const unsigned short pq = f2bf(p);
          Pb[rbase + col] = pq;
          rsum += bf2f(pq);
        }
        rsum += __shfl_xor(rsum, 1); rsum += __shfl_xor(rsum, 2);
        rsum += __shfl_xor(rsum, 4); rsum += __shfl_xor(rsum, 8);
        if (lr == 0) psum[wc * 256 + rloc] = rsum;
      }
    }
    __syncthreads();
    if (tid < 256) {
      const float v = psum[tid] + psum[256 + tid] + psum[512 + tid] + psum[768 + tid];
      lpart[((size_t)b * Sn + m0 + tid) * 8 + ((rem & 3) * 2 + tt)] = v;
    }
  });
}

// ---------------------------------------------------------------- PV (core A, reduce fused)
__global__ __launch_bounds__(512, 2) void pv_kernel(
    const unsigned short* __restrict__ P, const unsigned short* __restrict__ vT,
    const float* __restrict__ lpart, const float* __restrict__ masks,
    const unsigned short* __restrict__ qbf, float* __restrict__ out) {
  __shared__ __align__(16) unsigned short lds[4 * BUFS_A];
  const int orig = blockIdx.x;                    // 256 blocks
  const int wg = (orig & 7) * 32 + (orig >> 3);
  const int b = wg >> 5;
  const int rem = wg & 31;
  const int m0 = (rem >> 2) * 256, n0 = (rem & 3) * 256;
  const unsigned short* Ag = P + (size_t)b * Sn * Sn + (size_t)m0 * Sn;
  const unsigned short* Bg = vT + (size_t)b * Dn * Sn + (size_t)n0 * Sn;
  f32x4 acc[8][4];
  gemmA(Ag, Sn, Bg, Sn, Sn, lds, acc);

  const int tid = threadIdx.x;
  const int l = tid & 63, w = tid >> 6;
  const int wr = w >> 2, wc = w & 3;
  const int lr = l & 15, lk = l >> 4;

  __syncthreads();               // staging LDS dead; reuse for scale
  float* lsc = (float*)lds;      // 256 per-row scales
  if (tid < 256) {
    const float4* p4 = (const float4*)(lpart + ((size_t)b * Sn + m0 + tid) * 8);
    float4 a4 = p4[0], b4 = p4[1];
    const float sum = ((a4.x + a4.y) + (a4.z + a4.w)) + ((b4.x + b4.y) + (b4.z + b4.w));
    lsc[tid] = masks[b * Sn + m0 + tid] / sum;
  }
  __syncthreads();

  #pragma unroll
  for (int mi = 0; mi < 8; mi++) {
    #pragma unroll
    for (int j = 0; j < 4; j++) {
      const int rloc = wr * 128 + mi * 16 + lk * 4 + j;
      const float sc = lsc[rloc];
      const size_t rbase = ((size_t)b * Sn + m0 + rloc) * Dn;
      #pragma unroll
      for (int ni = 0; ni < 4; ni++) {
        const int col = n0 + wc * 64 + ni * 16 + lr;
        out[rbase + col] = acc[mi][ni][j] * sc + bf2f(qbf[rbase + col]);
      }
    }
  }
}

// ---------------------------------------------------------------- launch
extern "C" void kernel_launch(void* const* d_in, const int* in_sizes, int n_in,
                              void* d_out, int out_size, void* d_ws, size_t ws_size,
                              hipStream_t stream) {
  const float* x  = (const float*)d_in[0];
  const float* Wq = (const float*)d_in[1];
  const float* bq = (const float*)d_in[2];
  const float* Wk = (const float*)d_in[3];
  const float* bk = (const float*)d_in[4];
  const float* Wv = (const float*)d_in[5];
  const float* bv = (const float*)d_in[6];
  float* out = (float*)d_out;

  char* ws = (char*)d_ws;
  size_t off = 0;
  auto alloc = [&](size_t bytes) {
    char* p = ws + off;
    off += (bytes + 255) & ~(size_t)255;
    return p;
  };
  unsigned short* xbf = (unsigned short*)alloc((size_t)Mtot * Dn * 2);
  unsigned short* qbf = (unsigned short*)alloc((size_t)Mtot * Dn * 2);
  unsigned short* kbf = (unsigned short*)alloc((size_t)Mtot * Dn * 2);
  unsigned short* vT  = (unsigned short*)alloc((size_t)Bn * Dn * Sn * 2);
  unsigned short* P   = (unsigned short*)alloc((size_t)Bn * Sn * Sn * 2);
  unsigned short* Wt  = (unsigned short*)alloc((size_t)3 * Dn * Dn * 2);
  float* masks = (float*)alloc((size_t)Mtot * 4);
  float* lpart = (float*)alloc((size_t)Mtot * 8 * 4);

  prep_kernel<<<Mtot / 4, 256, 0, stream>>>(x, xbf, masks);
  wt_kernel<<<dim3(32, 32, 3), 256, 0, stream>>>(Wq, Wk, Wv, Wt);
  qk_kernel<<<512, 512, 0, stream>>>(xbf, Wt, bq, bk, qbf, kbf);
  scores_kernel<<<256, 512, 0, stream>>>(qbf, kbf, masks, P, lpart);
  v_kernel<<<512, 512, 0, stream>>>(xbf, Wt, bv, vT);
  pv_kernel<<<256, 512, 0, stream>>>(P, vT, lpart, masks, qbf, out);
}

// Round 12
// 274.382 us; speedup vs baseline: 1.4724x; 1.4724x over previous
//
#include <hip/hip_runtime.h>

#define DEV __device__ __forceinline__

typedef __attribute__((ext_vector_type(8))) short bf16x8;
typedef __attribute__((ext_vector_type(4))) float f32x4;

static constexpr int Bn = 8;
static constexpr int Sn = 2048;
static constexpr int Dn = 1024;
static constexpr int Mtot = Bn * Sn;   // 16384

// core B (qkv): ring-3, tile 256x128, BK=32 -> 24KB/buf, 72KB total, 2 blk/CU
static constexpr int ABUF = 8192;      // shorts: A 256x32
static constexpr int TBUF = 12288;     // shorts per ring buffer
// core A (scores/pv): ring-4, tile 256x256, BK=32 -> 32KB/buf, 128KB, 1 blk/CU
static constexpr int BUFS_A = 16384;   // shorts per ring buffer
static constexpr int BHALF_A = 8192;   // shorts: A half (256x32)

DEV void gload_lds16(const void* g, void* l) {
  __builtin_amdgcn_global_load_lds(
      (const __attribute__((address_space(1))) void*)g,
      (__attribute__((address_space(3))) void*)l, 16, 0, 0);
}

DEV float bf2f(unsigned short u) {
  union { unsigned int i; float f; } c;
  c.i = ((unsigned int)u) << 16;
  return c.f;
}
DEV unsigned short f2bf(float f) {
  union { float f; unsigned int i; } c;
  c.f = f;
  unsigned int lsb = (c.i >> 16) & 1u;
  return (unsigned short)((c.i + 0x7fffu + lsb) >> 16);
}

// ---------------------------------------------------------------- prep
__global__ __launch_bounds__(256) void prep_kernel(const float* __restrict__ x,
                                                   unsigned short* __restrict__ xbf,
                                                   float* __restrict__ masks) {
  const int w = threadIdx.x >> 6, l = threadIdx.x & 63;
  const int row = blockIdx.x * 4 + w;
  const float* xr = x + (size_t)row * Dn;
  unsigned short* xo = xbf + (size_t)row * Dn;
  float s = 0.f;
  #pragma unroll
  for (int i = 0; i < 4; i++) {
    float4 v = ((const float4*)xr)[i * 64 + l];
    s += (v.x + v.y) + (v.z + v.w);
    unsigned int p0 = (unsigned int)f2bf(v.x) | ((unsigned int)f2bf(v.y) << 16);
    unsigned int p1 = (unsigned int)f2bf(v.z) | ((unsigned int)f2bf(v.w) << 16);
    *(uint2*)&xo[i * 256 + l * 4] = make_uint2(p0, p1);
  }
  #pragma unroll
  for (int off = 32; off > 0; off >>= 1) s += __shfl_xor(s, off);
  if (l == 0) masks[row] = sinf(fabsf(s));
}

// ---------------------------------------------------------------- Wt
__global__ __launch_bounds__(256) void wt_kernel(const float* __restrict__ Wq,
                                                 const float* __restrict__ Wk,
                                                 const float* __restrict__ Wv,
                                                 unsigned short* __restrict__ Wt) {
  const float* W = blockIdx.z == 0 ? Wq : (blockIdx.z == 1 ? Wk : Wv);
  unsigned short* out = Wt + (size_t)blockIdx.z * Dn * Dn;
  __shared__ float tile[32][33];
  const int r0 = blockIdx.y * 32, c0 = blockIdx.x * 32;
  const int t = threadIdx.x;
  {
    const int r = t >> 3, c4 = (t & 7) * 4;
    float4 v = *(const float4*)&W[(size_t)(r0 + r) * Dn + c0 + c4];
    tile[r][c4 + 0] = v.x; tile[r][c4 + 1] = v.y;
    tile[r][c4 + 2] = v.z; tile[r][c4 + 3] = v.w;
  }
  __syncthreads();
  {
    const int f = t >> 3, d4 = (t & 7) * 4;
    unsigned short o[4];
    #pragma unroll
    for (int i = 0; i < 4; i++) o[i] = f2bf(tile[d4 + i][f]);
    unsigned int p0 = (unsigned int)o[0] | ((unsigned int)o[1] << 16);
    unsigned int p1 = (unsigned int)o[2] | ((unsigned int)o[3] << 16);
    *(uint2*)&out[(size_t)(c0 + f) * Dn + r0 + d4] = make_uint2(p0, p1);
  }
}

// ---------------------------------------------------------------- core B:
// 256x128 tile, BK=32, 8 waves (4Mx2N, per-wave 64x64), ring-3, distance-2
// staging, counted vmcnt(3), one barrier/tile, 2 blocks/CU. 16x16x32 MFMA.
DEV void gemmB(const unsigned short* __restrict__ Ag, int lda,
               const unsigned short* __restrict__ Bg, int ldb,
               int K, unsigned short* lds, f32x4 acc[4][4]) {
  const int tid = threadIdx.x;
  const int l = tid & 63, w = tid >> 6;
  const int wr = w >> 1, wc = w & 1;
  const int lr = l & 15, lk = l >> 4;

  #pragma unroll
  for (int mi = 0; mi < 4; mi++)
    #pragma unroll
    for (int ni = 0; ni < 4; ni++)
      #pragma unroll
      for (int q = 0; q < 4; q++) acc[mi][ni][q] = 0.f;

  int offA[4], offB[4];
  #pragma unroll
  for (int mi = 0; mi < 4; mi++) {
    const int row = wr * 64 + mi * 16 + lr;
    offA[mi] = (row * 4 + (lk ^ ((row >> 1) & 3))) * 8;
  }
  #pragma unroll
  for (int ni = 0; ni < 4; ni++) {
    const int row = wc * 64 + ni * 16 + lr;
    offB[ni] = (row * 4 + (lk ^ ((row >> 1) & 3))) * 8;
  }
  int sA[2], dA[2], sB, dB;
  #pragma unroll
  for (int i = 0; i < 2; i++) {
    const int ci = i * 512 + tid;
    const int row = ci >> 2, c = (ci & 3) ^ ((row >> 1) & 3);
    sA[i] = row * lda + c * 8;
    dA[i] = ci * 8;
  }
  {
    const int ci = tid;
    const int row = ci >> 2, c = (ci & 3) ^ ((row >> 1) & 3);
    sB = row * ldb + c * 8;
    dB = ci * 8;
  }

  const int NT = K >> 5;
  unsigned short* bc = lds;
  unsigned short* b1 = lds + TBUF;
  unsigned short* b2 = lds + 2 * TBUF;

  #pragma unroll
  for (int t = 0; t < 2; t++) {
    unsigned short* bf = lds + t * TBUF;
    gload_lds16(Ag + sA[0] + t * 32, bf + dA[0]);
    gload_lds16(Ag + sA[1] + t * 32, bf + dA[1]);
    gload_lds16(Bg + sB + t * 32, bf + ABUF + dB);
  }
  asm volatile("s_waitcnt vmcnt(3)\n\ts_barrier" ::: "memory");

  for (int t = 0; t < NT; t++) {
    const bool st = (t + 2 < NT);
    const int kt = (t + 2) * 32;

    bf16x8 af[4], bv[4];
    #pragma unroll
    for (int mi = 0; mi < 4; mi++) af[mi] = *(const bf16x8*)(bc + offA[mi]);
    #pragma unroll
    for (int ni = 0; ni < 4; ni++) bv[ni] = *(const bf16x8*)(bc + ABUF + offB[ni]);

    if (st) {
      gload_lds16(Ag + sA[0] + kt, b2 + dA[0]);
      gload_lds16(Ag + sA[1] + kt, b2 + dA[1]);
    }
    __builtin_amdgcn_s_setprio(1);
    #pragma unroll
    for (int mi = 0; mi < 4; mi++) {
      acc[mi][0] = __builtin_amdgcn_mfma_f32_16x16x32_bf16(af[mi], bv[0], acc[mi][0], 0, 0, 0);
      acc[mi][1] = __builtin_amdgcn_mfma_f32_16x16x32_bf16(af[mi], bv[1], acc[mi][1], 0, 0, 0);
    }
    __builtin_amdgcn_s_setprio(0);
    if (st) {
      gload_lds16(Bg + sB + kt, b2 + ABUF + dB);
    }
    __builtin_amdgcn_s_setprio(1);
    #pragma unroll
    for (int mi = 0; mi < 4; mi++) {
      acc[mi][2] = __builtin_amdgcn_mfma_f32_16x16x32_bf16(af[mi], bv[2], acc[mi][2], 0, 0, 0);
      acc[mi][3] = __builtin_amdgcn_mfma_f32_16x16x32_bf16(af[mi], bv[3], acc[mi][3], 0, 0, 0);
    }
    __builtin_amdgcn_s_setprio(0);

    if (t + 2 < NT) {
      asm volatile("s_waitcnt vmcnt(3)\n\ts_barrier" ::: "memory");
    } else if (t + 1 < NT) {
      asm volatile("s_waitcnt vmcnt(0)\n\ts_barrier" ::: "memory");
    }
    unsigned short* tmp = bc; bc = b1; b1 = b2; b2 = tmp;
  }
}

// ---------------------------------------------------------------- core A:
// 256x256 tile, BK=32, 8 waves (2Mx4N, per-wave 128x64), ring-4, distance-3
// staging, counted vmcnt(8), one barrier/tile, 1 block/CU. 16x16x32 MFMA.
DEV void gemmA(const unsigned short* __restrict__ Ag, int lda,
               const unsigned short* __restrict__ Bg, int ldb,
               int K, unsigned short* lds, f32x4 acc[8][4]) {
  const int tid = threadIdx.x;
  const int l = tid & 63, w = tid >> 6;
  const int wr = w >> 2, wc = w & 3;
  const int lr = l & 15, lk = l >> 4;

  #pragma unroll
  for (int mi = 0; mi < 8; mi++)
    #pragma unroll
    for (int ni = 0; ni < 4; ni++)
      #pragma unroll
      for (int q = 0; q < 4; q++) acc[mi][ni][q] = 0.f;

  int offA[8], offB[4];
  #pragma unroll
  for (int mi = 0; mi < 8; mi++) {
    const int row = wr * 128 + mi * 16 + lr;
    const int L = row >> 1, p = ((row & 1) * 4 + lk) ^ (L & 7);
    offA[mi] = L * 64 + p * 8;
  }
  #pragma unroll
  for (int ni = 0; ni < 4; ni++) {
    const int row = wc * 64 + ni * 16 + lr;
    const int L = row >> 1, p = ((row & 1) * 4 + lk) ^ (L & 7);
    offB[ni] = L * 64 + p * 8;
  }
  int sA[2], sB[2], dO[2];
  #pragma unroll
  for (int i = 0; i < 2; i++) {
    const int ci = i * 512 + tid;
    const int L = ci >> 3, p = ci & 7, e = p ^ (L & 7);
    const int grow = 2 * L + (e >> 2), gkc = e & 3;
    sA[i] = grow * lda + gkc * 8;
    sB[i] = grow * ldb + gkc * 8;
    dO[i] = ci * 8;
  }

  const int NT = K >> 5;
  #pragma unroll
  for (int t = 0; t < 3; t++) {
    unsigned short* bf = lds + t * BUFS_A;
    gload_lds16(Ag + sA[0] + t * 32, bf + dO[0]);
    gload_lds16(Ag + sA[1] + t * 32, bf + dO[1]);
    gload_lds16(Bg + sB[0] + t * 32, bf + BHALF_A + dO[0]);
    gload_lds16(Bg + sB[1] + t * 32, bf + BHALF_A + dO[1]);
  }
  asm volatile("s_waitcnt vmcnt(8)\n\ts_barrier" ::: "memory");

  for (int t = 0; t < NT; t++) {
    unsigned short* bufc = lds + (t & 3) * BUFS_A;
    unsigned short* bufs = lds + ((t + 3) & 3) * BUFS_A;
    const bool st = (t + 3 < NT);
    const int kt = (t + 3) * 32;

    bf16x8 af[8], bv[4];
    #pragma unroll
    for (int mi = 0; mi < 8; mi++) af[mi] = *(const bf16x8*)(bufc + offA[mi]);
    bv[0] = *(const bf16x8*)(bufc + BHALF_A + offB[0]);
    bv[1] = *(const bf16x8*)(bufc + BHALF_A + offB[1]);
    if (st) {
      gload_lds16(Ag + sA[0] + kt, bufs + dO[0]);
      gload_lds16(Ag + sA[1] + kt, bufs + dO[1]);
    }
    __builtin_amdgcn_s_setprio(1);
    #pragma unroll
    for (int mi = 0; mi < 8; mi++) {
      acc[mi][0] = __builtin_amdgcn_mfma_f32_16x16x32_bf16(af[mi], bv[0], acc[mi][0], 0, 0, 0);
      acc[mi][1] = __builtin_amdgcn_mfma_f32_16x16x32_bf16(af[mi], bv[1], acc[mi][1], 0, 0, 0);
    }
    __builtin_amdgcn_s_setprio(0);
    bv[2] = *(const bf16x8*)(bufc + BHALF_A + offB[2]);
    bv[3] = *(const bf16x8*)(bufc + BHALF_A + offB[3]);
    if (st) {
      gload_lds16(Bg + sB[0] + kt, bufs + BHALF_A + dO[0]);
      gload_lds16(Bg + sB[1] + kt, bufs + BHALF_A + dO[1]);
    }
    __builtin_amdgcn_s_setprio(1);
    #pragma unroll
    for (int mi = 0; mi < 8; mi++) {
      acc[mi][2] = __builtin_amdgcn_mfma_f32_16x16x32_bf16(af[mi], bv[2], acc[mi][2], 0, 0, 0);
      acc[mi][3] = __builtin_amdgcn_mfma_f32_16x16x32_bf16(af[mi], bv[3], acc[mi][3], 0, 0, 0);
    }
    __builtin_amdgcn_s_setprio(0);

    if (t < NT - 3) {
      asm volatile("s_waitcnt vmcnt(8)\n\ts_barrier" ::: "memory");
    } else if (t == NT - 3) {
      asm volatile("s_waitcnt vmcnt(4)\n\ts_barrier" ::: "memory");
    } else if (t == NT - 2) {
      asm volatile("s_waitcnt vmcnt(0)\n\ts_barrier" ::: "memory");
    }
  }
}

// ---------------------------------------------------------------- QKV (core B)
__global__ __launch_bounds__(512, 4) void qkv_kernel(
    const unsigned short* __restrict__ xbf, const unsigned short* __restrict__ Wt,
    const float* __restrict__ bq, const float* __restrict__ bk,
    const float* __restrict__ bv_,
    unsigned short* __restrict__ qo, unsigned short* __restrict__ ko,
    unsigned short* __restrict__ vT) {
  __shared__ __align__(16) unsigned short lds[3 * TBUF];
  const int orig = blockIdx.x;                     // 1536 blocks
  const int wg = (orig & 7) * 192 + (orig >> 3);   // bijective XCD swizzle
  const int which = wg >> 9;
  const int rem = wg & 511;
  const int m0 = (rem >> 3) * 256, n0 = (rem & 7) * 128;
  const unsigned short* Ag = xbf + (size_t)m0 * Dn;
  const unsigned short* Bg = Wt + (size_t)which * Dn * Dn + (size_t)n0 * Dn;
  f32x4 acc[4][4];
  gemmB(Ag, Dn, Bg, Dn, Dn, lds, acc);

  const float* bias = which == 0 ? bq : (which == 1 ? bk : bv_);
  const int tid = threadIdx.x;
  const int l = tid & 63, w = tid >> 6;
  const int wr = w >> 1, wc = w & 1;
  const int lr = l & 15, lk = l >> 4;

  if (which < 2) {
    unsigned short* out = which == 0 ? qo : ko;
    #pragma unroll
    for (int mi = 0; mi < 4; mi++) {
      #pragma unroll
      for (int ni = 0; ni < 4; ni++) {
        const int col = n0 + wc * 64 + ni * 16 + lr;
        const float bcol = bias[col];
        #pragma unroll
        for (int j = 0; j < 4; j++) {
          const int row = m0 + wr * 64 + mi * 16 + lk * 4 + j;
          out[(size_t)row * Dn + col] = f2bf(fmaxf(acc[mi][ni][j] + bcol, 0.f));
        }
      }
    }
  } else {
    // single-pass transpose: [128 d][256 s] swizzled LDS buffer (64KB)
    const int b = m0 >> 11;
    const int s0g = m0 & (Sn - 1);
    __syncthreads();  // staging LDS dead
    #pragma unroll
    for (int mi = 0; mi < 4; mi++) {
      const int sc = wr * 16 + mi * 4 + lk;   // 8B chunk of 4 s-values
      #pragma unroll
      for (int ni = 0; ni < 4; ni++) {
        const int d = wc * 64 + ni * 16 + lr;
        const float bcol = bias[n0 + d];
        unsigned short o0 = f2bf(fmaxf(acc[mi][ni][0] + bcol, 0.f));
        unsigned short o1 = f2bf(fmaxf(acc[mi][ni][1] + bcol, 0.f));
        unsigned short o2 = f2bf(fmaxf(acc[mi][ni][2] + bcol, 0.f));
        unsigned short o3 = f2bf(fmaxf(acc[mi][ni][3] + bcol, 0.f));
        const int scp = sc ^ (d & 63);
        *(uint2*)&lds[d * 256 + scp * 4] =
            make_uint2((unsigned int)o0 | ((unsigned int)o1 << 16),
                       (unsigned int)o2 | ((unsigned int)o3 << 16));
      }
    }
    __syncthreads();
    #pragma unroll
    for (int it = 0; it < 16; it++) {
      const int lin = it * 512 + tid;
      const int d = lin >> 6, sc = lin & 63;
      const int scp = sc ^ (d & 63);
      uint2 v = *(const uint2*)&lds[d * 256 + scp * 4];
      *(uint2*)&vT[((size_t)b * Dn + n0 + d) * Sn + s0g + sc * 4] = v;
    }
  }
}

// ---------------------------------------------------------------- scores (core A)
__global__ __launch_bounds__(512, 2) void scores_kernel(
    const unsigned short* __restrict__ qbf, const unsigned short* __restrict__ kbf,
    const float* __restrict__ masks, unsigned short* __restrict__ P,
    float* __restrict__ lpart) {
  __shared__ __align__(16) unsigned short lds[4 * BUFS_A];
  const int orig = blockIdx.x;                    // 512 blocks
  const int wg = (orig & 7) * 64 + (orig >> 3);
  const int b = wg >> 6;
  const int rem = wg & 63;
  const int m0 = (rem >> 3) * 256, n0 = (rem & 7) * 256;
  const unsigned short* Ag = qbf + ((size_t)b * Sn + m0) * Dn;
  const unsigned short* Bg = kbf + ((size_t)b * Sn + n0) * Dn;
  f32x4 acc[8][4];
  gemmA(Ag, Dn, Bg, Dn, Dn, lds, acc);

  const int tid = threadIdx.x;
  const int l = tid & 63, w = tid >> 6;
  const int wr = w >> 2, wc = w & 3;
  const int lr = l & 15, lk = l >> 4;

  __syncthreads();               // staging LDS dead; reuse for psum
  float* psum = (float*)lds;     // [4 wc][256 rows]

  float mkv[4];
  #pragma unroll
  for (int ni = 0; ni < 4; ni++) mkv[ni] = masks[b * Sn + n0 + wc * 64 + ni * 16 + lr];

  unsigned short* Pb = P + (size_t)b * Sn * Sn;
  #pragma unroll
  for (int mi = 0; mi < 8; mi++) {
    #pragma unroll
    for (int j = 0; j < 4; j++) {
      const int rloc = wr * 128 + mi * 16 + lk * 4 + j;
      const size_t rbase = (size_t)(m0 + rloc) * Sn;
      float rsum = 0.f;
      #pragma unroll
      for (int ni = 0; ni < 4; ni++) {
        const int col = n0 + wc * 64 + ni * 16 + lr;
        const float p = (mkv[ni] == 0.f) ? 0.f : __expf(acc[mi][ni][j] * 0.03125f);
        const unsigned short pq = f2bf(p);
        Pb[rbase + col] = pq;
        rsum += bf2f(pq);
      }
      rsum += __shfl_xor(rsum, 1); rsum += __shfl_xor(rsum, 2);
      rsum += __shfl_xor(rsum, 4); rsum += __shfl_xor(rsum, 8);
      if (lr == 0) psum[wc * 256 + rloc] = rsum;
    }
  }
  __syncthreads();
  if (tid < 256) {
    const float v = psum[tid] + psum[256 + tid] + psum[512 + tid] + psum[768 + tid];
    lpart[((size_t)b * Sn + m0 + tid) * 8 + (rem & 7)] = v;
  }
}

// ---------------------------------------------------------------- PV (core A)
// reduce fused: per-row scale = mask/sum(lpart) computed into LDS post-GEMM.
__global__ __launch_bounds__(512, 2) void pv_kernel(
    const unsigned short* __restrict__ P, const unsigned short* __restrict__ vT,
    const float* __restrict__ lpart, const float* __restrict__ masks,
    const unsigned short* __restrict__ qbf, float* __restrict__ out) {
  __shared__ __align__(16) unsigned short lds[4 * BUFS_A];
  const int orig = blockIdx.x;                    // 256 blocks
  const int wg = (orig & 7) * 32 + (orig >> 3);
  const int b = wg >> 5;
  const int rem = wg & 31;
  const int m0 = (rem >> 2) * 256, n0 = (rem & 3) * 256;
  const unsigned short* Ag = P + (size_t)b * Sn * Sn + (size_t)m0 * Sn;
  const unsigned short* Bg = vT + (size_t)b * Dn * Sn + (size_t)n0 * Sn;
  f32x4 acc[8][4];
  gemmA(Ag, Sn, Bg, Sn, Sn, lds, acc);

  const int tid = threadIdx.x;
  const int l = tid & 63, w = tid >> 6;
  const int wr = w >> 2, wc = w & 3;
  const int lr = l & 15, lk = l >> 4;

  __syncthreads();               // staging LDS dead; reuse for scale
  float* lsc = (float*)lds;      // 256 per-row scales
  if (tid < 256) {
    const float4* p4 = (const float4*)(lpart + ((size_t)b * Sn + m0 + tid) * 8);
    float4 a4 = p4[0], b4 = p4[1];
    const float sum = ((a4.x + a4.y) + (a4.z + a4.w)) + ((b4.x + b4.y) + (b4.z + b4.w));
    lsc[tid] = masks[b * Sn + m0 + tid] / sum;
  }
  __syncthreads();

  #pragma unroll
  for (int mi = 0; mi < 8; mi++) {
    #pragma unroll
    for (int j = 0; j < 4; j++) {
      const int rloc = wr * 128 + mi * 16 + lk * 4 + j;
      const float sc = lsc[rloc];
      const size_t rbase = ((size_t)b * Sn + m0 + rloc) * Dn;
      #pragma unroll
      for (int ni = 0; ni < 4; ni++) {
        const int col = n0 + wc * 64 + ni * 16 + lr;
        out[rbase + col] = acc[mi][ni][j] * sc + bf2f(qbf[rbase + col]);
      }
    }
  }
}

// ---------------------------------------------------------------- launch
extern "C" void kernel_launch(void* const* d_in, const int* in_sizes, int n_in,
                              void* d_out, int out_size, void* d_ws, size_t ws_size,
                              hipStream_t stream) {
  const float* x  = (const float*)d_in[0];
  const float* Wq = (const float*)d_in[1];
  const float* bq = (const float*)d_in[2];
  const float* Wk = (const float*)d_in[3];
  const float* bk = (const float*)d_in[4];
  const float* Wv = (const float*)d_in[5];
  const float* bv = (const float*)d_in[6];
  float* out = (float*)d_out;

  char* ws = (char*)d_ws;
  size_t off = 0;
  auto alloc = [&](size_t bytes) {
    char* p = ws + off;
    off += (bytes + 255) & ~(size_t)255;
    return p;
  };
  unsigned short* xbf = (unsigned short*)alloc((size_t)Mtot * Dn * 2);
  unsigned short* qbf = (unsigned short*)alloc((size_t)Mtot * Dn * 2);
  unsigned short* kbf = (unsigned short*)alloc((size_t)Mtot * Dn * 2);
  unsigned short* vT  = (unsigned short*)alloc((size_t)Bn * Dn * Sn * 2);
  unsigned short* P   = (unsigned short*)alloc((size_t)Bn * Sn * Sn * 2);
  unsigned short* Wt  = (unsigned short*)alloc((size_t)3 * Dn * Dn * 2);
  float* masks = (float*)alloc((size_t)Mtot * 4);
  float* lpart = (float*)alloc((size_t)Mtot * 8 * 4);

  prep_kernel<<<Mtot / 4, 256, 0, stream>>>(x, xbf, masks);
  wt_kernel<<<dim3(32, 32, 3), 256, 0, stream>>>(Wq, Wk, Wv, Wt);
  qkv_kernel<<<1536, 512, 0, stream>>>(xbf, Wt, bq, bk, bv, qbf, kbf, vT);
  scores_kernel<<<512, 512, 0, stream>>>(qbf, kbf, masks, P, lpart);
  pv_kernel<<<256, 512, 0, stream>>>(P, vT, lpart, masks, qbf, out);
}